// Round 20
// baseline (72.380 us; speedup 1.0000x reference)
//
#include <hip/hip_runtime.h>
#include <math.h>

#define BB 8
#define NN 2048
#define DD 256
#define NP 2049
#define AVP 2052
#define E1 0.36787944117144233f
#define PADK 40         // LDS f16 row stride (80 B = 5*16B)
#define ITERS 20

typedef _Float16 f16;
typedef __attribute__((ext_vector_type(8))) _Float16 f16x8;
typedef __attribute__((ext_vector_type(4))) float f32x4;
typedef __attribute__((ext_vector_type(2))) float f32x2;

#define DEC0(DW) __builtin_amdgcn_cvt_pk_f32_fp8((int)(DW), false)
#define DEC1(DW) __builtin_amdgcn_cvt_pk_f32_fp8((int)(DW), true)

// ---- split_cvt: fp32 -> f16 (16B stores) + row norms (32-lane rows) ----
__global__ __launch_bounds__(256) void split_cvt(const float* __restrict__ d1,
                                                 const float* __restrict__ d2,
                                                 f16* __restrict__ A16,
                                                 f16* __restrict__ B16,
                                                 float* __restrict__ n1,
                                                 float* __restrict__ n2) {
    const float* src = blockIdx.z ? d2 : d1;
    f16* dst = blockIdx.z ? B16 : A16;
    float* nn = blockIdx.z ? n2 : n1;
    const int b = blockIdx.y;
    const int row = blockIdx.x * 8 + (threadIdx.x >> 5);
    const int e0 = (threadIdx.x & 31) * 8;
    const size_t base = ((size_t)b * NN + row) * DD + e0;
    f32x4 v0 = *(const f32x4*)(src + base);
    f32x4 v1 = *(const f32x4*)(src + base + 4);
    f16x8 h;
    float s = 0.f;
    #pragma unroll
    for (int e = 0; e < 4; ++e) {
        h[e] = (f16)v0[e]; h[e + 4] = (f16)v1[e];
        s = fmaf(v0[e], v0[e], s);
        s = fmaf(v1[e], v1[e], s);
    }
    *(f16x8*)(dst + base) = h;
    #pragma unroll
    for (int off = 1; off < 32; off <<= 1) s += __shfl_xor(s, off);
    if ((threadIdx.x & 31) == 0) nn[b * NN + row] = s;
}

// ==== 128x256-tile fp16 MFMA GEMM: A-fragments direct from L2     ====
// ==== (no A staging), B double-buffered in LDS, in-loop P-zero    ====
// ==== plain stores, compare-based zero detect.                    ====
__global__ __launch_bounds__(512) void gemm128(const f16* __restrict__ A16,
                                               const f16* __restrict__ B16,
                                               const float* __restrict__ n1,
                                               const float* __restrict__ n2,
                                               unsigned char* __restrict__ Kc,
                                               int* __restrict__ flags,
                                               int* __restrict__ zflags,
                                               float* __restrict__ out) {
    __shared__ f16 Bs[2][256 * PADK];
    __shared__ int anyq[2];

    const int b = blockIdx.z;
    const int rt = blockIdx.x, ct = blockIdx.y;   // xcd = rt % 8 (A panels pinned)
    const int n0 = rt * 128, m0 = ct * 256;
    const int t = threadIdx.x;                    // 0..511
    const int wave = t >> 6, lane = t & 63;
    const int wrow = (wave >> 2) * 64;            // 2x4 wave grid: 64x64 out/wave
    const int wcol = (wave & 3) * 64;
    const f16* A  = A16 + ((size_t)b * NN + n0) * DD;
    const f16* Bm = B16 + ((size_t)b * NN + m0) * DD;
    float* ob = out + (size_t)b * NP * NP;

    const int rowB1 = t >> 2, qk = (t & 3) * 8;
    const int rowB2 = 128 + rowB1;
    if (t < 2) anyq[t] = 0;

    f32x4 zero = {0.f, 0.f, 0.f, 0.f};
    f32x4 acc[4][4];
    #pragma unroll
    for (int i = 0; i < 4; ++i)
        #pragma unroll
        for (int j = 0; j < 4; ++j) acc[i][j] = zero;

    const int rb = lane & 15;
    const int kg = (lane >> 4) * 8;

    // A fragment base pointers (L2-resident panel; 16 full lines/instr)
    const f16* Arow[4];
    #pragma unroll
    for (int f = 0; f < 4; ++f)
        Arow[f] = A + (size_t)(wrow + f * 16 + rb) * DD + kg;

    // prologue: stage B step 0, start B loads for step 1
    f16x8 pb1 = *(const f16x8*)(Bm + (size_t)rowB1 * DD + qk);
    f16x8 pb2 = *(const f16x8*)(Bm + (size_t)rowB2 * DD + qk);
    *(f16x8*)&Bs[0][rowB1 * PADK + qk] = pb1;
    *(f16x8*)&Bs[0][rowB2 * PADK + qk] = pb2;
    pb1 = *(const f16x8*)(Bm + (size_t)rowB1 * DD + 32 + qk);
    pb2 = *(const f16x8*)(Bm + (size_t)rowB2 * DD + 32 + qk);
    __syncthreads();

    const int pc = m0 + (t & 31) * 4;   // dense: lanes 0-31 cover 128 floats solid
    const int prow0 = n0 + (t >> 5);
    int cur = 0;

    #pragma unroll
    for (int s = 0; s < 8; ++s) {
        f16x8 af[4], bf[4];
        #pragma unroll
        for (int f = 0; f < 4; ++f)
            af[f] = *(const f16x8*)(Arow[f] + s * 32);
        #pragma unroll
        for (int f = 0; f < 4; ++f)
            bf[f] = *(const f16x8*)&Bs[cur][(wcol + f * 16 + rb) * PADK + kg];
        #pragma unroll
        for (int i = 0; i < 4; ++i)
            #pragma unroll
            for (int j = 0; j < 4; ++j)
                acc[i][j] = __builtin_amdgcn_mfma_f32_16x16x32_f16(bf[j], af[i], acc[i][j], 0, 0, 0);

        // unconditional dense P=0 pre-write (plain stores -> L2 ack)
        {
            int row = prow0 + s * 16;
            *(f32x4*)&ob[(size_t)row * NP + pc] = zero;
            *(f32x4*)&ob[(size_t)row * NP + pc + 128] = zero;
        }

        if (s < 7) {
            *(f16x8*)&Bs[cur ^ 1][rowB1 * PADK + qk] = pb1;
            *(f16x8*)&Bs[cur ^ 1][rowB2 * PADK + qk] = pb2;
            if (s < 6) {
                int k0 = (s + 2) * 32;
                pb1 = *(const f16x8*)(Bm + (size_t)rowB1 * DD + k0 + qk);
                pb2 = *(const f16x8*)(Bm + (size_t)rowB2 * DD + k0 + qk);
            }
        }
        __syncthreads();
        cur ^= 1;
    }

    // ---- epilogue: compare-based zero detect; exp/pack only if nonzero ----
    const int mg = (lane >> 4) * 4;
    float rn_[4];
    f32x4 cn_[4];
    #pragma unroll
    for (int i = 0; i < 4; ++i)
        rn_[i] = n1[b * NN + n0 + wrow + i * 16 + rb];
    #pragma unroll
    for (int j = 0; j < 4; ++j)
        cn_[j] = *(const f32x4*)&n2[b * NN + m0 + wcol + j * 16 + mg];

    int nzany = 0;
    #pragma unroll
    for (int i = 0; i < 4; ++i)
        #pragma unroll
        for (int j = 0; j < 4; ++j) {
            f32x4 a = acc[i][j];
            nzany |= (rn_[i] + cn_[j].x - 2.f * a.x < 7.5f);
            nzany |= (rn_[i] + cn_[j].y - 2.f * a.y < 7.5f);
            nzany |= (rn_[i] + cn_[j].z - 2.f * a.z < 7.5f);
            nzany |= (rn_[i] + cn_[j].w - 2.f * a.w < 7.5f);
        }
    if (nzany) anyq[wcol >> 7] = 1;
    __syncthreads();
    const int anyblk = anyq[0] | anyq[1];

    if (anyblk) {   // rare path: compute exp, pack fp8, store K
        #pragma unroll
        for (int i = 0; i < 4; ++i) {
            int n = wrow + i * 16 + rb;
            unsigned char* orow = Kc + ((size_t)b * NN + n0 + n) * NN + m0 + wcol + mg;
            #pragma unroll
            for (int j = 0; j < 4; ++j) {
                f32x4 a = acc[i][j];
                float v0 = __expf(-fmaxf(rn_[i] + cn_[j].x - 2.f * a.x, 0.f));
                float v1 = __expf(-fmaxf(rn_[i] + cn_[j].y - 2.f * a.y, 0.f));
                float v2 = __expf(-fmaxf(rn_[i] + cn_[j].z - 2.f * a.z, 0.f));
                float v3 = __expf(-fmaxf(rn_[i] + cn_[j].w - 2.f * a.w, 0.f));
                int p = __builtin_amdgcn_cvt_pk_fp8_f32(v0, v1, 0, false);
                p = __builtin_amdgcn_cvt_pk_fp8_f32(v2, v3, p, true);
                *(unsigned int*)(orow + j * 16) = (unsigned int)p;
            }
        }
    }
    if (t < 2) flags[b * 256 + rt * 16 + ct * 2 + t] = anyq[t] ? 1 : 0;
    if (t == 0) zflags[b * 128 + rt * 8 + ct] = anyblk ? 0 : 1;
}

// ==== Sinkhorn iterations + dustbin P + nonzero-tile P rewrite =======
__global__ __launch_bounds__(1024) void sinkhorn_iter(
    const unsigned char* __restrict__ Kc,
    const int* __restrict__ flags,
    float* __restrict__ av, float* __restrict__ bv,
    float* __restrict__ out)
{
    const int batch = blockIdx.x;
    const int t = threadIdx.x;
    const int lane = t & 63, w = t >> 6;
    __shared__ float a_sh[NN], b_sh[NN], rs_sh[NN];
    __shared__ float p8[128][9];
    __shared__ float wred[16];
    __shared__ float scal[2];
    __shared__ int flg[256];
    __shared__ int rowNZ[16], colNZ[16], anyNZ;

    if (t < 256) flg[t] = flags[batch * 256 + t];
    if (t == 0) anyNZ = 0;
    __syncthreads();
    if (t < 16) {
        int o = 0;
        #pragma unroll
        for (int j = 0; j < 16; ++j) o |= flg[t * 16 + j];
        rowNZ[t] = o;
        if (o) atomicOr(&anyNZ, 1);
    } else if (t < 32) {
        int j = t - 16, o = 0;
        #pragma unroll
        for (int i = 0; i < 16; ++i) o |= flg[i * 16 + j];
        colNZ[j] = o;
    }
    __syncthreads();
    const unsigned char* Kb = Kc + (size_t)batch * NN * NN;
    float* avb = av + (size_t)batch * AVP;
    float* bvb = bv + (size_t)batch * AVP;
    float* ob = out + (size_t)batch * NP * NP;

    if (!anyNZ) {
        float bMv = 1.f, bcore = 1.f, aNv = 0.f, acore = 0.f;
        for (int it = 0; it < ITERS; ++it) {
            float Sb = 2048.f * bcore + bMv;
            aNv = 2048.f / (E1 * Sb);
            acore = 1.0f / (E1 * bMv);
            float Sa = 2048.f * acore + aNv;
            bcore = 1.0f / (E1 * aNv);
            bMv = 2048.f / (E1 * Sa);
        }
        avb[t] = acore; avb[t + 1024] = acore;
        bvb[t] = bcore; bvb[t + 1024] = bcore;
        if (t == 0) { avb[NN] = aNv; bvb[NN] = bMv; }
        ob[(size_t)t * NP + NN] = acore * E1 * bMv;
        ob[(size_t)(t + 1024) * NP + NN] = acore * E1 * bMv;
        ob[(size_t)NN * NP + t] = aNv * E1 * bcore;
        ob[(size_t)NN * NP + t + 1024] = aNv * E1 * bcore;
        if (t == 0) ob[(size_t)NN * NP + NN] = aNv * E1 * bMv;
        return;
    }

    b_sh[t] = 1.f; b_sh[t + 1024] = 1.f;
    float bMv = 1.f, aNv = 0.f;
    const int r = t >> 3, c8 = (t & 7) * 16;
    __syncthreads();

    for (int it = 0; it < ITERS; ++it) {
        float sb = b_sh[t] + b_sh[t + 1024];
        #pragma unroll
        for (int off = 1; off < 64; off <<= 1) sb += __shfl_xor(sb, off);
        if (lane == 0) wred[w] = sb;
        rs_sh[t] = 0.f; rs_sh[t + 1024] = 0.f;
        __syncthreads();
        if (t == 0) {
            float S = bMv;
            #pragma unroll
            for (int k = 0; k < 16; ++k) S += wred[k];
            scal[0] = 2048.f / (E1 * S);
        }
        __syncthreads();
        aNv = scal[0];

        for (int i = 0; i < 16; ++i) {
            if (!rowNZ[i]) continue;
            float acc = 0.f;
            for (int j = 0; j < 16; ++j) {
                if (!flg[i * 16 + j]) continue;
                const unsigned char* p = Kb + (size_t)(i * 128 + r) * NN + j * 128 + c8;
                uint4 kv = *(const uint4*)p;
                const float* bp = &b_sh[j * 128 + c8];
                unsigned int dwv[4] = {kv.x, kv.y, kv.z, kv.w};
                #pragma unroll
                for (int q = 0; q < 4; ++q) {
                    f32x2 u0 = DEC0(dwv[q]); f32x2 u1 = DEC1(dwv[q]);
                    acc += u0.x * bp[4 * q] + u0.y * bp[4 * q + 1]
                         + u1.x * bp[4 * q + 2] + u1.y * bp[4 * q + 3];
                }
            }
            p8[r][t & 7] = acc;
            __syncthreads();
            if (t < 128) {
                float s = 0.f;
                #pragma unroll
                for (int k = 0; k < 8; ++k) s += p8[t][k];
                rs_sh[i * 128 + t] = s;
            }
            __syncthreads();
        }
        float ebM = E1 * bMv;
        float a0 = 1.0f / (rs_sh[t] + ebM);
        float a1 = 1.0f / (rs_sh[t + 1024] + ebM);
        a_sh[t] = a0; a_sh[t + 1024] = a1;
        float sa = a0 + a1;
        #pragma unroll
        for (int off = 1; off < 64; off <<= 1) sa += __shfl_xor(sa, off);
        if (lane == 0) wred[w] = sa;
        __syncthreads();
        if (t == 0) {
            float S = aNv;
            #pragma unroll
            for (int k = 0; k < 16; ++k) S += wred[k];
            scal[1] = 2048.f / (E1 * S);
        }
        rs_sh[t] = 0.f; rs_sh[t + 1024] = 0.f;
        __syncthreads();

        for (int j = 0; j < 16; ++j) {
            if (!colNZ[j]) continue;
            float acc = 0.f;
            int col = j * 128 + r;
            for (int i = 0; i < 16; ++i) {
                if (!flg[i * 16 + j]) continue;
                #pragma unroll
                for (int e = 0; e < 16; ++e) {
                    int rr2 = i * 128 + c8 + e;
                    f32x2 u = DEC0((unsigned int)Kb[(size_t)rr2 * NN + col]);
                    acc += u.x * a_sh[rr2];
                }
            }
            p8[r][t & 7] = acc;
            __syncthreads();
            if (t < 128) {
                float s = 0.f;
                #pragma unroll
                for (int k = 0; k < 8; ++k) s += p8[t][k];
                rs_sh[j * 128 + t] = s;
            }
            __syncthreads();
        }
        float eaN = E1 * aNv;
        b_sh[t] = 1.0f / (rs_sh[t] + eaN);
        b_sh[t + 1024] = 1.0f / (rs_sh[t + 1024] + eaN);
        bMv = scal[1];
        __syncthreads();
    }
    avb[t] = a_sh[t]; avb[t + 1024] = a_sh[t + 1024];
    bvb[t] = b_sh[t]; bvb[t + 1024] = b_sh[t + 1024];
    if (t == 0) { avb[NN] = aNv; bvb[NN] = bMv; }
    // dustbin P
    ob[(size_t)t * NP + NN] = a_sh[t] * E1 * bMv;
    ob[(size_t)(t + 1024) * NP + NN] = a_sh[t + 1024] * E1 * bMv;
    ob[(size_t)NN * NP + t] = aNv * E1 * b_sh[t];
    ob[(size_t)NN * NP + t + 1024] = aNv * E1 * b_sh[t + 1024];
    if (t == 0) ob[(size_t)NN * NP + NN] = aNv * E1 * bMv;

    // rewrite P for flagged 128x128 tiles (zeros already pre-written else)
    const int fr = t >> 3;                 // 0..127
    const int fc = (t & 7) * 16;           // 0..112
    for (int i = 0; i < 16; ++i) {
        if (!rowNZ[i]) continue;
        for (int j = 0; j < 16; ++j) {
            if (!flg[i * 16 + j]) continue;
            int row = i * 128 + fr;
            int col = j * 128 + fc;
            float a = a_sh[row];
            const unsigned char* kp = Kb + (size_t)row * NN + col;
            uint4 kv = *(const uint4*)kp;
            unsigned int dwv[4] = {kv.x, kv.y, kv.z, kv.w};
            float* op = ob + (size_t)row * NP + col;
            #pragma unroll
            for (int q = 0; q < 4; ++q) {
                f32x2 u0 = DEC0(dwv[q]); f32x2 u1 = DEC1(dwv[q]);
                f32x4 val;
                val.x = a * u0.x * b_sh[col + 4 * q];
                val.y = a * u0.y * b_sh[col + 4 * q + 1];
                val.z = a * u1.x * b_sh[col + 4 * q + 2];
                val.w = a * u1.y * b_sh[col + 4 * q + 3];
                *(f32x4*)(op + 4 * q) = val;
            }
        }
    }
}

// =====================================================================
extern "C" void kernel_launch(void* const* d_in, const int* in_sizes, int n_in,
                              void* d_out, int out_size, void* d_ws, size_t ws_size,
                              hipStream_t stream) {
    const float* d1 = (const float*)d_in[0];
    const float* d2 = (const float*)d_in[1];
    float* out = (float*)d_out;

    const size_t KCB = (size_t)BB * NN * NN;            // 33.5 MB fp8
    const size_t F16C = (size_t)BB * NN * DD;
    unsigned char* Kc = (unsigned char*)d_ws;
    f16* A16 = (f16*)(Kc + KCB);
    f16* B16 = A16 + F16C;
    int* flags = (int*)(B16 + F16C);                    // BB*256
    int* zflags = flags + BB * 256;                     // BB*128
    float* av = (float*)(zflags + BB * 128);
    float* bv = av + (size_t)BB * AVP;
    float* n1 = bv + (size_t)BB * AVP;
    float* n2 = n1 + (size_t)BB * NN;

    split_cvt<<<dim3(NN / 8, BB, 2), 256, 0, stream>>>(d1, d2, A16, B16, n1, n2);
    gemm128<<<dim3(16, 8, BB), 512, 0, stream>>>(A16, B16, n1, n2, Kc, flags, zflags, out);
    sinkhorn_iter<<<BB, 1024, 0, stream>>>(Kc, flags, av, bv, out);
}

// Round 21
// 51.650 us; speedup vs baseline: 1.4014x; 1.4014x over previous
//
#include <hip/hip_runtime.h>
#include <math.h>

#define BB 8
#define NN 2048
#define DD 256
#define NP 2049
#define AVP 2052
#define E1 0.36787944117144233f
#define PADK 40         // LDS f16 row stride (80 B = 5*16B)
#define ITERS 20

typedef _Float16 f16;
typedef __attribute__((ext_vector_type(8))) _Float16 f16x8;
typedef __attribute__((ext_vector_type(4))) float f32x4;
typedef __attribute__((ext_vector_type(2))) float f32x2;

#define DEC0(DW) __builtin_amdgcn_cvt_pk_f32_fp8((int)(DW), false)
#define DEC1(DW) __builtin_amdgcn_cvt_pk_f32_fp8((int)(DW), true)

// ---- split_cvt: fp32 -> f16 (16B stores) + row norms (32-lane rows) ----
__global__ __launch_bounds__(256) void split_cvt(const float* __restrict__ d1,
                                                 const float* __restrict__ d2,
                                                 f16* __restrict__ A16,
                                                 f16* __restrict__ B16,
                                                 float* __restrict__ n1,
                                                 float* __restrict__ n2) {
    const float* src = blockIdx.z ? d2 : d1;
    f16* dst = blockIdx.z ? B16 : A16;
    float* nn = blockIdx.z ? n2 : n1;
    const int b = blockIdx.y;
    const int row = blockIdx.x * 8 + (threadIdx.x >> 5);
    const int e0 = (threadIdx.x & 31) * 8;
    const size_t base = ((size_t)b * NN + row) * DD + e0;
    f32x4 v0 = *(const f32x4*)(src + base);
    f32x4 v1 = *(const f32x4*)(src + base + 4);
    f16x8 h;
    float s = 0.f;
    #pragma unroll
    for (int e = 0; e < 4; ++e) {
        h[e] = (f16)v0[e]; h[e + 4] = (f16)v1[e];
        s = fmaf(v0[e], v0[e], s);
        s = fmaf(v1[e], v1[e], s);
    }
    *(f16x8*)(dst + base) = h;
    #pragma unroll
    for (int off = 1; off < 32; off <<= 1) s += __shfl_xor(s, off);
    if ((threadIdx.x & 31) == 0) nn[b * NN + row] = s;
}

// ==== 128x256-tile fp16 MFMA GEMM, dbuf 1-barrier K-loop,         ====
// ==== in-loop dense P-zero stores (PLAIN stores: ack from L2,     ====
// ==== cheap vmcnt drain at barriers, lazy writeback to HBM).      ====
__global__ __launch_bounds__(512) void gemm128(const f16* __restrict__ A16,
                                               const f16* __restrict__ B16,
                                               const float* __restrict__ n1,
                                               const float* __restrict__ n2,
                                               unsigned char* __restrict__ Kc,
                                               int* __restrict__ flags,
                                               int* __restrict__ zflags,
                                               float* __restrict__ out) {
    __shared__ f16 As[2][128 * PADK];
    __shared__ f16 Bs[2][256 * PADK];
    __shared__ int anyq[2];

    const int b = blockIdx.z;
    const int rt = blockIdx.x, ct = blockIdx.y;   // xcd = rt % 8 (A panels pinned)
    const int n0 = rt * 128, m0 = ct * 256;
    const int t = threadIdx.x;                    // 0..511
    const int wave = t >> 6, lane = t & 63;
    const int wrow = (wave >> 2) * 64;            // 2x4 wave grid: 64x64 out/wave
    const int wcol = (wave & 3) * 64;
    const f16* A  = A16 + ((size_t)b * NN + n0) * DD;
    const f16* Bm = B16 + ((size_t)b * NN + m0) * DD;
    float* ob = out + (size_t)b * NP * NP;

    const int rowA = t >> 2, qk = (t & 3) * 8;
    const int rowB2 = 128 + rowA;
    if (t < 2) anyq[t] = 0;

    f32x4 zero = {0.f, 0.f, 0.f, 0.f};
    f32x4 acc[4][4];
    #pragma unroll
    for (int i = 0; i < 4; ++i)
        #pragma unroll
        for (int j = 0; j < 4; ++j) acc[i][j] = zero;

    const int rb = lane & 15;
    const int kg = (lane >> 4) * 8;

    // prologue: stage step 0, start loads for step 1
    f16x8 pa  = *(const f16x8*)(A  + (size_t)rowA  * DD + qk);
    f16x8 pb1 = *(const f16x8*)(Bm + (size_t)rowA  * DD + qk);
    f16x8 pb2 = *(const f16x8*)(Bm + (size_t)rowB2 * DD + qk);
    *(f16x8*)&As[0][rowA  * PADK + qk] = pa;
    *(f16x8*)&Bs[0][rowA  * PADK + qk] = pb1;
    *(f16x8*)&Bs[0][rowB2 * PADK + qk] = pb2;
    pa  = *(const f16x8*)(A  + (size_t)rowA  * DD + 32 + qk);
    pb1 = *(const f16x8*)(Bm + (size_t)rowA  * DD + 32 + qk);
    pb2 = *(const f16x8*)(Bm + (size_t)rowB2 * DD + 32 + qk);
    __syncthreads();

    const int pc = m0 + (t & 31) * 4;   // dense: lanes 0-31 cover 128 floats solid
    const int prow0 = n0 + (t >> 5);
    int cur = 0;

    for (int s = 0; s < 8; ++s) {
        f16x8 af[4], bf[4];
        #pragma unroll
        for (int f = 0; f < 4; ++f) {
            af[f] = *(const f16x8*)&As[cur][(wrow + f * 16 + rb) * PADK + kg];
            bf[f] = *(const f16x8*)&Bs[cur][(wcol + f * 16 + rb) * PADK + kg];
        }
        #pragma unroll
        for (int i = 0; i < 4; ++i)
            #pragma unroll
            for (int j = 0; j < 4; ++j)
                acc[i][j] = __builtin_amdgcn_mfma_f32_16x16x32_f16(bf[j], af[i], acc[i][j], 0, 0, 0);

        // unconditional dense P=0 pre-write (plain stores -> L2 ack)
        {
            int row = prow0 + s * 16;
            *(f32x4*)&ob[(size_t)row * NP + pc] = zero;
            *(f32x4*)&ob[(size_t)row * NP + pc + 128] = zero;
        }

        if (s < 7) {
            *(f16x8*)&As[cur ^ 1][rowA  * PADK + qk] = pa;
            *(f16x8*)&Bs[cur ^ 1][rowA  * PADK + qk] = pb1;
            *(f16x8*)&Bs[cur ^ 1][rowB2 * PADK + qk] = pb2;
            if (s < 6) {
                int k0 = (s + 2) * 32;
                pa  = *(const f16x8*)(A  + (size_t)rowA  * DD + k0 + qk);
                pb1 = *(const f16x8*)(Bm + (size_t)rowA  * DD + k0 + qk);
                pb2 = *(const f16x8*)(Bm + (size_t)rowB2 * DD + k0 + qk);
            }
        }
        __syncthreads();
        cur ^= 1;
    }

    // ---- epilogue: compare-based zero detect; exp/pack only if nonzero ----
    const int mg = (lane >> 4) * 4;
    float rn_[4];
    f32x4 cn_[4];
    #pragma unroll
    for (int i = 0; i < 4; ++i)
        rn_[i] = n1[b * NN + n0 + wrow + i * 16 + rb];
    #pragma unroll
    for (int j = 0; j < 4; ++j)
        cn_[j] = *(const f32x4*)&n2[b * NN + m0 + wcol + j * 16 + mg];

    int nzany = 0;
    #pragma unroll
    for (int i = 0; i < 4; ++i)
        #pragma unroll
        for (int j = 0; j < 4; ++j) {
            f32x4 a = acc[i][j];
            nzany |= (rn_[i] + cn_[j].x - 2.f * a.x < 7.5f);
            nzany |= (rn_[i] + cn_[j].y - 2.f * a.y < 7.5f);
            nzany |= (rn_[i] + cn_[j].z - 2.f * a.z < 7.5f);
            nzany |= (rn_[i] + cn_[j].w - 2.f * a.w < 7.5f);
        }
    if (nzany) anyq[wcol >> 7] = 1;
    __syncthreads();
    const int anyblk = anyq[0] | anyq[1];

    if (anyblk) {   // rare path: compute exp, pack fp8, store K
        #pragma unroll
        for (int i = 0; i < 4; ++i) {
            int n = wrow + i * 16 + rb;
            unsigned char* orow = Kc + ((size_t)b * NN + n0 + n) * NN + m0 + wcol + mg;
            #pragma unroll
            for (int j = 0; j < 4; ++j) {
                f32x4 a = acc[i][j];
                float v0 = __expf(-fmaxf(rn_[i] + cn_[j].x - 2.f * a.x, 0.f));
                float v1 = __expf(-fmaxf(rn_[i] + cn_[j].y - 2.f * a.y, 0.f));
                float v2 = __expf(-fmaxf(rn_[i] + cn_[j].z - 2.f * a.z, 0.f));
                float v3 = __expf(-fmaxf(rn_[i] + cn_[j].w - 2.f * a.w, 0.f));
                int p = __builtin_amdgcn_cvt_pk_fp8_f32(v0, v1, 0, false);
                p = __builtin_amdgcn_cvt_pk_fp8_f32(v2, v3, p, true);
                *(unsigned int*)(orow + j * 16) = (unsigned int)p;
            }
        }
    }
    if (t < 2) flags[b * 256 + rt * 16 + ct * 2 + t] = anyq[t] ? 1 : 0;
    if (t == 0) zflags[b * 128 + rt * 8 + ct] = anyblk ? 0 : 1;
}

// ==== Sinkhorn iterations + dustbin P + nonzero-tile P rewrite =======
__global__ __launch_bounds__(1024) void sinkhorn_iter(
    const unsigned char* __restrict__ Kc,
    const int* __restrict__ flags,
    float* __restrict__ av, float* __restrict__ bv,
    float* __restrict__ out)
{
    const int batch = blockIdx.x;
    const int t = threadIdx.x;
    const int lane = t & 63, w = t >> 6;
    __shared__ float a_sh[NN], b_sh[NN], rs_sh[NN];
    __shared__ float p8[128][9];
    __shared__ float wred[16];
    __shared__ float scal[2];
    __shared__ int flg[256];
    __shared__ int rowNZ[16], colNZ[16], anyNZ;

    if (t < 256) flg[t] = flags[batch * 256 + t];
    if (t == 0) anyNZ = 0;
    __syncthreads();
    if (t < 16) {
        int o = 0;
        #pragma unroll
        for (int j = 0; j < 16; ++j) o |= flg[t * 16 + j];
        rowNZ[t] = o;
        if (o) atomicOr(&anyNZ, 1);
    } else if (t < 32) {
        int j = t - 16, o = 0;
        #pragma unroll
        for (int i = 0; i < 16; ++i) o |= flg[i * 16 + j];
        colNZ[j] = o;
    }
    __syncthreads();
    const unsigned char* Kb = Kc + (size_t)batch * NN * NN;
    float* avb = av + (size_t)batch * AVP;
    float* bvb = bv + (size_t)batch * AVP;
    float* ob = out + (size_t)batch * NP * NP;

    if (!anyNZ) {
        float bMv = 1.f, bcore = 1.f, aNv = 0.f, acore = 0.f;
        for (int it = 0; it < ITERS; ++it) {
            float Sb = 2048.f * bcore + bMv;
            aNv = 2048.f / (E1 * Sb);
            acore = 1.0f / (E1 * bMv);
            float Sa = 2048.f * acore + aNv;
            bcore = 1.0f / (E1 * aNv);
            bMv = 2048.f / (E1 * Sa);
        }
        avb[t] = acore; avb[t + 1024] = acore;
        bvb[t] = bcore; bvb[t + 1024] = bcore;
        if (t == 0) { avb[NN] = aNv; bvb[NN] = bMv; }
        ob[(size_t)t * NP + NN] = acore * E1 * bMv;
        ob[(size_t)(t + 1024) * NP + NN] = acore * E1 * bMv;
        ob[(size_t)NN * NP + t] = aNv * E1 * bcore;
        ob[(size_t)NN * NP + t + 1024] = aNv * E1 * bcore;
        if (t == 0) ob[(size_t)NN * NP + NN] = aNv * E1 * bMv;
        return;
    }

    b_sh[t] = 1.f; b_sh[t + 1024] = 1.f;
    float bMv = 1.f, aNv = 0.f;
    const int r = t >> 3, c8 = (t & 7) * 16;
    __syncthreads();

    for (int it = 0; it < ITERS; ++it) {
        float sb = b_sh[t] + b_sh[t + 1024];
        #pragma unroll
        for (int off = 1; off < 64; off <<= 1) sb += __shfl_xor(sb, off);
        if (lane == 0) wred[w] = sb;
        rs_sh[t] = 0.f; rs_sh[t + 1024] = 0.f;
        __syncthreads();
        if (t == 0) {
            float S = bMv;
            #pragma unroll
            for (int k = 0; k < 16; ++k) S += wred[k];
            scal[0] = 2048.f / (E1 * S);
        }
        __syncthreads();
        aNv = scal[0];

        for (int i = 0; i < 16; ++i) {
            if (!rowNZ[i]) continue;
            float acc = 0.f;
            for (int j = 0; j < 16; ++j) {
                if (!flg[i * 16 + j]) continue;
                const unsigned char* p = Kb + (size_t)(i * 128 + r) * NN + j * 128 + c8;
                uint4 kv = *(const uint4*)p;
                const float* bp = &b_sh[j * 128 + c8];
                unsigned int dwv[4] = {kv.x, kv.y, kv.z, kv.w};
                #pragma unroll
                for (int q = 0; q < 4; ++q) {
                    f32x2 u0 = DEC0(dwv[q]); f32x2 u1 = DEC1(dwv[q]);
                    acc += u0.x * bp[4 * q] + u0.y * bp[4 * q + 1]
                         + u1.x * bp[4 * q + 2] + u1.y * bp[4 * q + 3];
                }
            }
            p8[r][t & 7] = acc;
            __syncthreads();
            if (t < 128) {
                float s = 0.f;
                #pragma unroll
                for (int k = 0; k < 8; ++k) s += p8[t][k];
                rs_sh[i * 128 + t] = s;
            }
            __syncthreads();
        }
        float ebM = E1 * bMv;
        float a0 = 1.0f / (rs_sh[t] + ebM);
        float a1 = 1.0f / (rs_sh[t + 1024] + ebM);
        a_sh[t] = a0; a_sh[t + 1024] = a1;
        float sa = a0 + a1;
        #pragma unroll
        for (int off = 1; off < 64; off <<= 1) sa += __shfl_xor(sa, off);
        if (lane == 0) wred[w] = sa;
        __syncthreads();
        if (t == 0) {
            float S = aNv;
            #pragma unroll
            for (int k = 0; k < 16; ++k) S += wred[k];
            scal[1] = 2048.f / (E1 * S);
        }
        rs_sh[t] = 0.f; rs_sh[t + 1024] = 0.f;
        __syncthreads();

        for (int j = 0; j < 16; ++j) {
            if (!colNZ[j]) continue;
            float acc = 0.f;
            int col = j * 128 + r;
            for (int i = 0; i < 16; ++i) {
                if (!flg[i * 16 + j]) continue;
                #pragma unroll
                for (int e = 0; e < 16; ++e) {
                    int rr2 = i * 128 + c8 + e;
                    f32x2 u = DEC0((unsigned int)Kb[(size_t)rr2 * NN + col]);
                    acc += u.x * a_sh[rr2];
                }
            }
            p8[r][t & 7] = acc;
            __syncthreads();
            if (t < 128) {
                float s = 0.f;
                #pragma unroll
                for (int k = 0; k < 8; ++k) s += p8[t][k];
                rs_sh[j * 128 + t] = s;
            }
            __syncthreads();
        }
        float eaN = E1 * aNv;
        b_sh[t] = 1.0f / (rs_sh[t] + eaN);
        b_sh[t + 1024] = 1.0f / (rs_sh[t + 1024] + eaN);
        bMv = scal[1];
        __syncthreads();
    }
    avb[t] = a_sh[t]; avb[t + 1024] = a_sh[t + 1024];
    bvb[t] = b_sh[t]; bvb[t + 1024] = b_sh[t + 1024];
    if (t == 0) { avb[NN] = aNv; bvb[NN] = bMv; }
    // dustbin P
    ob[(size_t)t * NP + NN] = a_sh[t] * E1 * bMv;
    ob[(size_t)(t + 1024) * NP + NN] = a_sh[t + 1024] * E1 * bMv;
    ob[(size_t)NN * NP + t] = aNv * E1 * b_sh[t];
    ob[(size_t)NN * NP + t + 1024] = aNv * E1 * b_sh[t + 1024];
    if (t == 0) ob[(size_t)NN * NP + NN] = aNv * E1 * bMv;

    // rewrite P for flagged 128x128 tiles (zeros already pre-written else)
    const int fr = t >> 3;                 // 0..127
    const int fc = (t & 7) * 16;           // 0..112
    for (int i = 0; i < 16; ++i) {
        if (!rowNZ[i]) continue;
        for (int j = 0; j < 16; ++j) {
            if (!flg[i * 16 + j]) continue;
            int row = i * 128 + fr;
            int col = j * 128 + fc;
            float a = a_sh[row];
            const unsigned char* kp = Kb + (size_t)row * NN + col;
            uint4 kv = *(const uint4*)kp;
            unsigned int dwv[4] = {kv.x, kv.y, kv.z, kv.w};
            float* op = ob + (size_t)row * NP + col;
            #pragma unroll
            for (int q = 0; q < 4; ++q) {
                f32x2 u0 = DEC0(dwv[q]); f32x2 u1 = DEC1(dwv[q]);
                f32x4 val;
                val.x = a * u0.x * b_sh[col + 4 * q];
                val.y = a * u0.y * b_sh[col + 4 * q + 1];
                val.z = a * u1.x * b_sh[col + 4 * q + 2];
                val.w = a * u1.y * b_sh[col + 4 * q + 3];
                *(f32x4*)(op + 4 * q) = val;
            }
        }
    }
}

// =====================================================================
extern "C" void kernel_launch(void* const* d_in, const int* in_sizes, int n_in,
                              void* d_out, int out_size, void* d_ws, size_t ws_size,
                              hipStream_t stream) {
    const float* d1 = (const float*)d_in[0];
    const float* d2 = (const float*)d_in[1];
    float* out = (float*)d_out;

    const size_t KCB = (size_t)BB * NN * NN;            // 33.5 MB fp8
    const size_t F16C = (size_t)BB * NN * DD;
    unsigned char* Kc = (unsigned char*)d_ws;
    f16* A16 = (f16*)(Kc + KCB);
    f16* B16 = A16 + F16C;
    int* flags = (int*)(B16 + F16C);                    // BB*256
    int* zflags = flags + BB * 256;                     // BB*128
    float* av = (float*)(zflags + BB * 128);
    float* bv = av + (size_t)BB * AVP;
    float* n1 = bv + (size_t)BB * AVP;
    float* n2 = n1 + (size_t)BB * NN;

    split_cvt<<<dim3(NN / 8, BB, 2), 256, 0, stream>>>(d1, d2, A16, B16, n1, n2);
    gemm128<<<dim3(16, 8, BB), 512, 0, stream>>>(A16, B16, n1, n2, Kc, flags, zflags, out);
    sinkhorn_iter<<<BB, 1024, 0, stream>>>(Kc, flags, av, bv, out);
}